// Round 10
// baseline (223.586 us; speedup 1.0000x reference)
//
#include <hip/hip_runtime.h>
#include <hip/hip_bf16.h>
#include <cstdint>

#define SEQ   2048
#define HID   1024
#define NH    16
#define HD    64
#define NB    2
#define MTOT  (NB*SEQ)   // 4096

typedef unsigned short u16;
typedef __bf16 bf16x8 __attribute__((ext_vector_type(8)));
typedef float  f32x4  __attribute__((ext_vector_type(4)));
typedef unsigned short u16x8 __attribute__((ext_vector_type(8)));

#if __has_builtin(__builtin_amdgcn_exp2f)
#define EXP2(x) __builtin_amdgcn_exp2f(x)
#else
#define EXP2(x) exp2f(x)
#endif

// global -> LDS direct copy, 16B per lane. Dest must be wave-uniform base + lane*16.
__device__ __forceinline__ void gll16(const void* g, void* l) {
    __builtin_amdgcn_global_load_lds(
        (const __attribute__((address_space(1))) uint32_t*)(uintptr_t)g,
        (__attribute__((address_space(3))) uint32_t*)(uint32_t)(uintptr_t)l,
        16, 0, 0);
}

__device__ __forceinline__ u16 f2bf(float f) {
    uint32_t u = __builtin_bit_cast(uint32_t, f);
    u += 0x7fffu + ((u >> 16) & 1u);
    return (u16)(u >> 16);
}

// ---------------- prep: x + positional encoding -> bf16 ----------------
__global__ void __launch_bounds__(256) prep_x_kernel(const float* __restrict__ x,
                                                     u16* __restrict__ xpe) {
    int t  = blockIdx.x * 256 + threadIdx.x;     // 0 .. 1M-1
    int i4 = t * 4;
    int m  = i4 >> 10;
    int k0 = i4 & (HID - 1);
    int s  = m & (SEQ - 1);
    const float c = -2.0f * 9.210340371976184f / 1024.0f;  // -2*ln(1e4)/HID
    float4 xv = *(const float4*)(x + i4);
    float vals[4] = {xv.x, xv.y, xv.z, xv.w};
    u16 o[4];
#pragma unroll
    for (int e = 0; e < 4; ++e) {
        int k = k0 + e;
        int i = k >> 1;
        float div = __expf((float)i * c);
        float ang = (float)s * div;
        float pe  = (k & 1) ? __cosf(ang) : __sinf(ang);
        o[e] = f2bf(vals[e] + pe);
    }
    uint2 o2;
    o2.x = (uint32_t)o[0] | ((uint32_t)o[1] << 16);
    o2.y = (uint32_t)o[2] | ((uint32_t)o[3] << 16);
    *(uint2*)(xpe + i4) = o2;
}

// ---------------- weights fp32 -> bf16, all four in one launch ----------------
__global__ void __launch_bounds__(256) convw4_kernel(const float* __restrict__ s0,
                                                     const float* __restrict__ s1,
                                                     const float* __restrict__ s2,
                                                     const float* __restrict__ s3,
                                                     u16* __restrict__ d0w, u16* __restrict__ d1w,
                                                     u16* __restrict__ d2w, u16* __restrict__ d3w) {
    int z = blockIdx.y;
    const float* src = (z == 0) ? s0 : (z == 1) ? s1 : (z == 2) ? s2 : s3;
    u16* dst = (z == 0) ? d0w : (z == 1) ? d1w : (z == 2) ? d2w : d3w;
    int t  = blockIdx.x * 256 + threadIdx.x;
    int i4 = t * 4;
    float4 v = *(const float4*)(src + i4);
    uint2 o2;
    o2.x = (uint32_t)f2bf(v.x) | ((uint32_t)f2bf(v.y) << 16);
    o2.y = (uint32_t)f2bf(v.z) | ((uint32_t)f2bf(v.w) << 16);
    *(uint2*)(dst + i4) = o2;
}

// ---------------- GEMM: C = A(M x K) @ W(N x K)^T + bias ----------------
// 128x128 tile, BK=32, 4 waves (2x2), double-buffered LDS, global_load_lds staging.
// MODE 0: bf16 out in [B][H][S][64] layout, scaled (for QKV; z picks weight).
// MODE 1: fp32 out flat [M][N].
template <int MODE>
__global__ void __launch_bounds__(256)
gemm128_kernel(const u16* __restrict__ A,
               const u16* __restrict__ B0, const u16* __restrict__ B1, const u16* __restrict__ B2,
               const float* __restrict__ bias0, const float* __restrict__ bias1, const float* __restrict__ bias2,
               void* __restrict__ O0, void* __restrict__ O1, void* __restrict__ O2) {
    const int K = HID;
    __shared__ u16 lds[2][2][128 * 32];   // [buf][A/B][row*32+col] swizzled, 32 KiB
    const int tid  = threadIdx.x;
    const int lane = tid & 63;
    const int wid  = tid >> 6;
    const int n0   = blockIdx.x * 128;
    const int m0   = blockIdx.y * 128;
    const int z    = blockIdx.z;
    const u16*  Bw   = (z == 0) ? B0 : (z == 1) ? B1 : B2;
    const float* bias = (z == 0) ? bias0 : (z == 1) ? bias1 : bias2;

    const int wr = wid >> 1, wc = wid & 1;
    const int l15 = lane & 15, l4 = lane >> 4;

    int offA[4], offB[4];
#pragma unroll
    for (int f = 0; f < 4; ++f) {
        int rA = wr * 64 + f * 16 + l15;
        offA[f] = rA * 64 + ((l4 ^ ((rA >> 1) & 3)) << 4);
        int rB = wc * 64 + f * 16 + l15;
        offB[f] = rB * 64 + ((l4 ^ ((rB >> 1) & 3)) << 4);
    }

    auto stage = [&](int buf, int k0) {
#pragma unroll
        for (int i = 0; i < 2; ++i) {
            int slot = tid + i * 256;
            int row  = slot >> 2;
            int g    = (slot & 3) ^ ((row >> 1) & 3);
            gll16(A  + (size_t)(m0 + row) * K + k0 + g * 8, &lds[buf][0][slot * 8]);
            gll16(Bw + (size_t)(n0 + row) * K + k0 + g * 8, &lds[buf][1][slot * 8]);
        }
    };

    f32x4 acc[4][4] = {};
    stage(0, 0);
    asm volatile("s_waitcnt vmcnt(0)" ::: "memory");
    __syncthreads();
    int cur = 0;
    for (int t = 0; t < K / 32; ++t) {
        if (t + 1 < K / 32) stage(cur ^ 1, (t + 1) * 32);
        const char* baA = (const char*)&lds[cur][0][0];
        const char* baB = (const char*)&lds[cur][1][0];
        bf16x8 af[4], bf[4];
#pragma unroll
        for (int f = 0; f < 4; ++f) af[f] = *(const bf16x8*)(baA + offA[f]);
#pragma unroll
        for (int f = 0; f < 4; ++f) bf[f] = *(const bf16x8*)(baB + offB[f]);
#pragma unroll
        for (int mi = 0; mi < 4; ++mi)
#pragma unroll
            for (int ni = 0; ni < 4; ++ni)
                acc[mi][ni] = __builtin_amdgcn_mfma_f32_16x16x32_bf16(af[mi], bf[ni], acc[mi][ni], 0, 0, 0);
        asm volatile("s_waitcnt vmcnt(0)" ::: "memory");
        __syncthreads();
        cur ^= 1;
    }

    float bi[4];
#pragma unroll
    for (int ni = 0; ni < 4; ++ni) bi[ni] = bias[n0 + wc * 64 + ni * 16 + l15];

    if (MODE == 0) {
        u16* out = (u16*)((z == 0) ? O0 : (z == 1) ? O1 : O2);
        // fold 1/sqrt(64) * log2(e) into Q so attention works in exp2 domain
        const float scale = (z == 0) ? 0.125f * 1.4426950408889634f : 1.0f;
#pragma unroll
        for (int mi = 0; mi < 4; ++mi)
#pragma unroll
            for (int ni = 0; ni < 4; ++ni) {
                int col = n0 + wc * 64 + ni * 16 + l15;
                int h = col >> 6, d = col & 63;
#pragma unroll
                for (int j = 0; j < 4; ++j) {
                    int row = m0 + wr * 64 + mi * 16 + (l4 << 2) + j;
                    int b = row >> 11, s = row & (SEQ - 1);
                    out[(size_t)((b * NH + h) * SEQ + s) * HD + d] =
                        f2bf((acc[mi][ni][j] + bi[ni]) * scale);
                }
            }
    } else {
        float* out = (float*)O0;
#pragma unroll
        for (int mi = 0; mi < 4; ++mi)
#pragma unroll
            for (int ni = 0; ni < 4; ++ni) {
                int col = n0 + wc * 64 + ni * 16 + l15;
#pragma unroll
                for (int j = 0; j < 4; ++j) {
                    int row = m0 + wr * 64 + mi * 16 + (l4 << 2) + j;
                    out[(size_t)row * HID + col] = acc[mi][ni][j] + bi[ni];
                }
            }
    }
}

// ---------------- flash attention v6 (global K, LDS V, 32q/wave) ----------------
// v5 post-mortem: LDS-bandwidth-bound (~2.9 GB LDS traffic/dispatch ~= 56us floor).
// v6 cuts LDS traffic ~2.4x:
//  - K never touches LDS: QK^T A-operand fragments are per-lane, loaded straight
//    from global. XCD-affine grid (bh%8 = XCD) keeps K streams L2/L1-resident.
//    K(t+1) prefetched into the same regs right after QK^T(t) consumes them.
//  - 32 q-rows/wave (2 swapped 16-q groups): every V/P LDS byte serves 2x rows.
// grid (32 bh, 16 qt) = 512 blocks, 256 thr / 4 waves, LDS 32KB, 1 barrier/tile.
__global__ void __launch_bounds__(256, 2)
attn_kernel(const u16* __restrict__ Q, const u16* __restrict__ Kp,
            const u16* __restrict__ V, u16* __restrict__ CTX) {
    __shared__ u16 Vt[2][64 * 64];     // [buf][d][key] swizzled: byte = d*128 + ((key*2)^((d&7)<<4))
    __shared__ u16 Plds[4][32 * 64];   // per-wave [q][key] swizzled: byte = q*128 + ((key*2)^((q&7)<<4))
    const int tid = threadIdx.x, lane = tid & 63, wid = tid >> 6;
    const int l15 = lane & 15, l4 = lane >> 4;
    const int bh = blockIdx.x;                 // bh on x -> XCD affinity (id%8 = bh%8)
    const size_t base = (size_t)bh * (SEQ * HD);
    const int q0 = blockIdx.y * 128 + wid * 32;

    // Q fragments (B-operand), 2 groups of 16 q-rows
    bf16x8 qf[2][2];
#pragma unroll
    for (int g = 0; g < 2; ++g)
#pragma unroll
        for (int kf = 0; kf < 2; ++kf)
            qf[g][kf] = *(const bf16x8*)(Q + base + (size_t)(q0 + g * 16 + l15) * HD + kf * 32 + l4 * 8);

    f32x4 acc[2][4] = {};              // [group][nd]: col=l15 -> d=nd*16+l15, row=l4*4+j -> q
    float m[2]    = {-__builtin_inff(), -__builtin_inff()};
    float lsum[2] = {0.f, 0.f};        // per-lane partials

    const int k2 = tid & 31;           // V staging: keys 2k2, 2k2+1
    const int d0 = (tid >> 5) * 8;     // d-group
    u16* Pw = Plds[wid];
    const u16* kPbase = Kp + base + (size_t)l15 * HD + l4 * 8;

    uint4 ka[8];                        // K fragments, current tile (ni*2+kf)
    auto loadK = [&](int kt) {
        const u16* p = kPbase + (size_t)kt * 64 * HD;
#pragma unroll
        for (int ni = 0; ni < 4; ++ni)
#pragma unroll
            for (int kf = 0; kf < 2; ++kf)
                ka[ni * 2 + kf] = *(const uint4*)(p + ni * 16 * HD + kf * 32);
    };

    auto writeV = [&](int buf, uint4 va, uint4 vb) {
        u16x8 pa = __builtin_bit_cast(u16x8, va);
        u16x8 pb = __builtin_bit_cast(u16x8, vb);
#pragma unroll
        for (int j = 0; j < 8; ++j) {
            uint32_t w = (uint32_t)pa[j] | ((uint32_t)pb[j] << 16);
            *(uint32_t*)((char*)&Vt[buf][0] + (d0 + j) * 128 + ((4 * k2) ^ (j << 4))) = w;
        }
    };

    // prologue: K0 -> regs, V0 -> regs -> Vt[0]
    loadK(0);
    {
        uint4 va = *(const uint4*)(V + base + (size_t)(2 * k2) * HD + d0);
        uint4 vb = *(const uint4*)(V + base + (size_t)(2 * k2 + 1) * HD + d0);
        writeV(0, va, vb);
    }
    __syncthreads();

    for (int t = 0; t < SEQ / 64; ++t) {
        const int buf = t & 1;
        const bool hn = (t + 1) < SEQ / 64;

        // ---- issue V(t+1) loads first (longest latency, consumed latest) ----
        uint4 va, vb;
        if (hn) {
            va = *(const uint4*)(V + base + (size_t)((t + 1) * 64 + 2 * k2) * HD + d0);
            vb = *(const uint4*)(V + base + (size_t)((t + 1) * 64 + 2 * k2 + 1) * HD + d0);
        }

        // ---- S^T = K @ Q^T, both groups share K frags ----
        f32x4 st[2][4] = {};
        __builtin_amdgcn_s_setprio(1);
#pragma unroll
        for (int ni = 0; ni < 4; ++ni) {
            bf16x8 k0 = __builtin_bit_cast(bf16x8, ka[ni * 2 + 0]);
            bf16x8 k1 = __builtin_bit_cast(bf16x8, ka[ni * 2 + 1]);
            st[0][ni] = __builtin_amdgcn_mfma_f32_16x16x32_bf16(k0, qf[0][0], st[0][ni], 0, 0, 0);
            st[0][ni] = __builtin_amdgcn_mfma_f32_16x16x32_bf16(k1, qf[0][1], st[0][ni], 0, 0, 0);
            st[1][ni] = __builtin_amdgcn_mfma_f32_16x16x32_bf16(k0, qf[1][0], st[1][ni], 0, 0, 0);
            st[1][ni] = __builtin_amdgcn_mfma_f32_16x16x32_bf16(k1, qf[1][1], st[1][ni], 0, 0, 0);
        }
        __builtin_amdgcn_s_setprio(0);

        // ---- K(t+1) prefetch into same regs (dead after QK) ----
        if (hn) loadK(t + 1);

        // ---- softmax per group, zero-shuffle common path (exp2 domain) ----
#pragma unroll
        for (int g = 0; g < 2; ++g) {
            float pmax = fmaxf(fmaxf(st[g][0][0], st[g][0][1]), fmaxf(st[g][0][2], st[g][0][3]));
#pragma unroll
            for (int ni = 1; ni < 4; ++ni)
                pmax = fmaxf(pmax, fmaxf(fmaxf(st[g][ni][0], st[g][ni][1]),
                                         fmaxf(st[g][ni][2], st[g][ni][3])));
            if (!__all(pmax <= m[g] + 8.0f)) {     // rare: real max growth
                float t0 = fmaxf(pmax, __shfl_xor(pmax, 16));
                t0 = fmaxf(t0, __shfl_xor(t0, 32));
                float mnew  = fmaxf(m[g], t0);
                float alpha = EXP2(m[g] - mnew);   // first tile: exp2(-inf)=0
                m[g] = mnew;
                lsum[g] *= alpha;
                float aj[4];
#pragma unroll
                for (int j = 0; j < 4; ++j) aj[j] = __shfl(alpha, l4 * 4 + j, 64);
#pragma unroll
                for (int nd = 0; nd < 4; ++nd)
#pragma unroll
                    for (int j = 0; j < 4; ++j) acc[g][nd][j] *= aj[j];
            }
            float rs = 0.f;
#pragma unroll
            for (int ni = 0; ni < 4; ++ni)
#pragma unroll
                for (int j = 0; j < 4; ++j) {
                    st[g][ni][j] = EXP2(st[g][ni][j] - m[g]);   // bounded by 2^8
                    rs += st[g][ni][j];
                }
            lsum[g] += rs;
        }

        // ---- stage V(t+1) (va/vb arrived under QK+softmax) ----
        if (hn) writeV(buf ^ 1, va, vb);

        // ---- P -> per-wave LDS (packed bf16 pairs), both groups ----
#pragma unroll
        for (int g = 0; g < 2; ++g)
#pragma unroll
            for (int ni = 0; ni < 4; ++ni)
#pragma unroll
                for (int jp = 0; jp < 2; ++jp) {
                    uint32_t w;
                    asm("v_cvt_pk_bf16_f32 %0, %1, %2" : "=v"(w)
                        : "v"(st[g][ni][2 * jp]), "v"(st[g][ni][2 * jp + 1]));
                    int key = ni * 16 + l4 * 4 + 2 * jp;
                    *(uint32_t*)((char*)Pw + (g * 16 + l15) * 128 +
                                 ((key * 2) ^ ((l15 & 7) << 4))) = w;
                }

        bf16x8 pf[2][2];
#pragma unroll
        for (int g = 0; g < 2; ++g)
#pragma unroll
            for (int kc = 0; kc < 2; ++kc)
                pf[g][kc] = *(const bf16x8*)((char*)Pw + (g * 16 + l15) * 128 +
                                             ((kc * 64 + l4 * 16) ^ ((l15 & 7) << 4)));

        // ---- ctx += P @ V, both groups share vf ----
        __builtin_amdgcn_s_setprio(1);
#pragma unroll
        for (int kc = 0; kc < 2; ++kc)
#pragma unroll
            for (int nd = 0; nd < 4; ++nd) {
                int dr = nd * 16 + l15;
                bf16x8 vf = *(const bf16x8*)((char*)&Vt[buf][0] + dr * 128 +
                                             ((kc * 64 + l4 * 16) ^ ((dr & 7) << 4)));
                acc[0][nd] = __builtin_amdgcn_mfma_f32_16x16x32_bf16(pf[0][kc], vf, acc[0][nd], 0, 0, 0);
                acc[1][nd] = __builtin_amdgcn_mfma_f32_16x16x32_bf16(pf[1][kc], vf, acc[1][nd], 0, 0, 0);
            }
        __builtin_amdgcn_s_setprio(0);

        // relaxed barrier: LDS ops only; K prefetch stays in flight across it.
        asm volatile("s_waitcnt lgkmcnt(0)" ::: "memory");
        __builtin_amdgcn_s_barrier();
        asm volatile("" ::: "memory");
    }

    // epilogue: reduce per-lane lsum, then ctx/l -> bf16 [B][S][HID]
    const int b = bh >> 4, h = bh & 15;
#pragma unroll
    for (int g = 0; g < 2; ++g) {
        float ls = lsum[g];
        ls += __shfl_xor(ls, 16);
        ls += __shfl_xor(ls, 32);      // q-uniform total for q=l15 (group g)
        float lj[4];
#pragma unroll
        for (int j = 0; j < 4; ++j) lj[j] = 1.0f / __shfl(ls, l4 * 4 + j, 64);
#pragma unroll
        for (int nd = 0; nd < 4; ++nd)
#pragma unroll
            for (int j = 0; j < 4; ++j) {
                int s = q0 + g * 16 + l4 * 4 + j;
                int d = nd * 16 + l15;
                CTX[((size_t)(b * SEQ + s)) * HID + h * HD + d] = f2bf(acc[g][nd][j] * lj[j]);
            }
    }
}

// ---------------- launch ----------------
extern "C" void kernel_launch(void* const* d_in, const int* in_sizes, int n_in,
                              void* d_out, int out_size, void* d_ws, size_t ws_size,
                              hipStream_t stream) {
    const float* x  = (const float*)d_in[0];
    const float* Wq = (const float*)d_in[1];
    const float* bq = (const float*)d_in[2];
    const float* Wk = (const float*)d_in[3];
    const float* bk = (const float*)d_in[4];
    const float* Wv = (const float*)d_in[5];
    const float* bv = (const float*)d_in[6];
    const float* Wo = (const float*)d_in[7];
    const float* bo = (const float*)d_in[8];
    float* out = (float*)d_out;

    char* ws = (char*)d_ws;
    u16* xpe = (u16*)(ws);                      // 8 MB : 4096x1024 bf16
    u16* wqb = (u16*)(ws + ((size_t)8  << 20)); // 2 MB each
    u16* wkb = (u16*)(ws + ((size_t)10 << 20));
    u16* wvb = (u16*)(ws + ((size_t)12 << 20));
    u16* wob = (u16*)(ws + ((size_t)14 << 20));
    u16* qb  = (u16*)(ws + ((size_t)16 << 20)); // 8 MB each, [B][H][S][64]
    u16* kb  = (u16*)(ws + ((size_t)24 << 20));
    u16* vb  = (u16*)(ws + ((size_t)32 << 20));
    u16* ctx = (u16*)(ws + ((size_t)40 << 20)); // 8 MB, [B][S][HID]

    prep_x_kernel<<<dim3(4096), dim3(256), 0, stream>>>(x, xpe);
    convw4_kernel<<<dim3(1024, 4), dim3(256), 0, stream>>>(Wq, Wk, Wv, Wo, wqb, wkb, wvb, wob);

    gemm128_kernel<0><<<dim3(8, 32, 3), dim3(256), 0, stream>>>(
        xpe, wqb, wkb, wvb, bq, bk, bv, qb, kb, vb);

    attn_kernel<<<dim3(32, 16), dim3(256), 0, stream>>>(qb, kb, vb, ctx);

    gemm128_kernel<1><<<dim3(8, 32, 1), dim3(256), 0, stream>>>(
        ctx, wob, wob, wob, bo, bo, bo, out, out, out);
}

// Round 11
// 199.466 us; speedup vs baseline: 1.1209x; 1.1209x over previous
//
#include <hip/hip_runtime.h>
#include <hip/hip_bf16.h>
#include <cstdint>

#define SEQ   2048
#define HID   1024
#define NH    16
#define HD    64
#define NB    2
#define MTOT  (NB*SEQ)   // 4096

typedef unsigned short u16;
typedef __bf16 bf16x8 __attribute__((ext_vector_type(8)));
typedef float  f32x4  __attribute__((ext_vector_type(4)));
typedef unsigned short u16x8 __attribute__((ext_vector_type(8)));

#if __has_builtin(__builtin_amdgcn_exp2f)
#define EXP2(x) __builtin_amdgcn_exp2f(x)
#else
#define EXP2(x) exp2f(x)
#endif

// global -> LDS direct copy, 16B per lane. Dest must be wave-uniform base + lane*16.
__device__ __forceinline__ void gll16(const void* g, void* l) {
    __builtin_amdgcn_global_load_lds(
        (const __attribute__((address_space(1))) uint32_t*)(uintptr_t)g,
        (__attribute__((address_space(3))) uint32_t*)(uint32_t)(uintptr_t)l,
        16, 0, 0);
}

__device__ __forceinline__ u16 f2bf(float f) {
    uint32_t u = __builtin_bit_cast(uint32_t, f);
    u += 0x7fffu + ((u >> 16) & 1u);
    return (u16)(u >> 16);
}

// ---------------- prep: x + positional encoding -> bf16 ----------------
__global__ void __launch_bounds__(256) prep_x_kernel(const float* __restrict__ x,
                                                     u16* __restrict__ xpe) {
    int t  = blockIdx.x * 256 + threadIdx.x;     // 0 .. 1M-1
    int i4 = t * 4;
    int m  = i4 >> 10;
    int k0 = i4 & (HID - 1);
    int s  = m & (SEQ - 1);
    const float c = -2.0f * 9.210340371976184f / 1024.0f;  // -2*ln(1e4)/HID
    float4 xv = *(const float4*)(x + i4);
    float vals[4] = {xv.x, xv.y, xv.z, xv.w};
    u16 o[4];
#pragma unroll
    for (int e = 0; e < 4; ++e) {
        int k = k0 + e;
        int i = k >> 1;
        float div = __expf((float)i * c);
        float ang = (float)s * div;
        float pe  = (k & 1) ? __cosf(ang) : __sinf(ang);
        o[e] = f2bf(vals[e] + pe);
    }
    uint2 o2;
    o2.x = (uint32_t)o[0] | ((uint32_t)o[1] << 16);
    o2.y = (uint32_t)o[2] | ((uint32_t)o[3] << 16);
    *(uint2*)(xpe + i4) = o2;
}

// ---------------- weights fp32 -> bf16, all four in one launch ----------------
__global__ void __launch_bounds__(256) convw4_kernel(const float* __restrict__ s0,
                                                     const float* __restrict__ s1,
                                                     const float* __restrict__ s2,
                                                     const float* __restrict__ s3,
                                                     u16* __restrict__ d0w, u16* __restrict__ d1w,
                                                     u16* __restrict__ d2w, u16* __restrict__ d3w) {
    int z = blockIdx.y;
    const float* src = (z == 0) ? s0 : (z == 1) ? s1 : (z == 2) ? s2 : s3;
    u16* dst = (z == 0) ? d0w : (z == 1) ? d1w : (z == 2) ? d2w : d3w;
    int t  = blockIdx.x * 256 + threadIdx.x;
    int i4 = t * 4;
    float4 v = *(const float4*)(src + i4);
    uint2 o2;
    o2.x = (uint32_t)f2bf(v.x) | ((uint32_t)f2bf(v.y) << 16);
    o2.y = (uint32_t)f2bf(v.z) | ((uint32_t)f2bf(v.w) << 16);
    *(uint2*)(dst + i4) = o2;
}

// ---------------- GEMM: C = A(M x K) @ W(N x K)^T + bias ----------------
// 128x128 tile, BK=32, 4 waves (2x2), double-buffered LDS, global_load_lds staging.
// MODE 0: bf16 out, flat [M][N] (= [B][S][HID]), Q-scale folded for z==0.
// MODE 1: fp32 out, flat [M][N].
template <int MODE>
__global__ void __launch_bounds__(256)
gemm128_kernel(const u16* __restrict__ A,
               const u16* __restrict__ B0, const u16* __restrict__ B1, const u16* __restrict__ B2,
               const float* __restrict__ bias0, const float* __restrict__ bias1, const float* __restrict__ bias2,
               void* __restrict__ O0, void* __restrict__ O1, void* __restrict__ O2) {
    const int K = HID;
    __shared__ u16 lds[2][2][128 * 32];   // [buf][A/B][row*32+col] swizzled, 32 KiB
    const int tid  = threadIdx.x;
    const int lane = tid & 63;
    const int wid  = tid >> 6;
    const int n0   = blockIdx.x * 128;
    const int m0   = blockIdx.y * 128;
    const int z    = blockIdx.z;
    const u16*  Bw   = (z == 0) ? B0 : (z == 1) ? B1 : B2;
    const float* bias = (z == 0) ? bias0 : (z == 1) ? bias1 : bias2;

    const int wr = wid >> 1, wc = wid & 1;
    const int l15 = lane & 15, l4 = lane >> 4;

    int offA[4], offB[4];
#pragma unroll
    for (int f = 0; f < 4; ++f) {
        int rA = wr * 64 + f * 16 + l15;
        offA[f] = rA * 64 + ((l4 ^ ((rA >> 1) & 3)) << 4);
        int rB = wc * 64 + f * 16 + l15;
        offB[f] = rB * 64 + ((l4 ^ ((rB >> 1) & 3)) << 4);
    }

    auto stage = [&](int buf, int k0) {
#pragma unroll
        for (int i = 0; i < 2; ++i) {
            int slot = tid + i * 256;
            int row  = slot >> 2;
            int g    = (slot & 3) ^ ((row >> 1) & 3);
            gll16(A  + (size_t)(m0 + row) * K + k0 + g * 8, &lds[buf][0][slot * 8]);
            gll16(Bw + (size_t)(n0 + row) * K + k0 + g * 8, &lds[buf][1][slot * 8]);
        }
    };

    f32x4 acc[4][4] = {};
    stage(0, 0);
    asm volatile("s_waitcnt vmcnt(0)" ::: "memory");
    __syncthreads();
    int cur = 0;
    for (int t = 0; t < K / 32; ++t) {
        if (t + 1 < K / 32) stage(cur ^ 1, (t + 1) * 32);
        const char* baA = (const char*)&lds[cur][0][0];
        const char* baB = (const char*)&lds[cur][1][0];
        bf16x8 af[4], bf[4];
#pragma unroll
        for (int f = 0; f < 4; ++f) af[f] = *(const bf16x8*)(baA + offA[f]);
#pragma unroll
        for (int f = 0; f < 4; ++f) bf[f] = *(const bf16x8*)(baB + offB[f]);
#pragma unroll
        for (int mi = 0; mi < 4; ++mi)
#pragma unroll
            for (int ni = 0; ni < 4; ++ni)
                acc[mi][ni] = __builtin_amdgcn_mfma_f32_16x16x32_bf16(af[mi], bf[ni], acc[mi][ni], 0, 0, 0);
        asm volatile("s_waitcnt vmcnt(0)" ::: "memory");
        __syncthreads();
        cur ^= 1;
    }

    float bi[4];
#pragma unroll
    for (int ni = 0; ni < 4; ++ni) bi[ni] = bias[n0 + wc * 64 + ni * 16 + l15];

    if (MODE == 0) {
        u16* out = (u16*)((z == 0) ? O0 : (z == 1) ? O1 : O2);
        // fold 1/sqrt(64) * log2(e) into Q so attention works in exp2 domain
        const float scale = (z == 0) ? 0.125f * 1.4426950408889634f : 1.0f;
#pragma unroll
        for (int mi = 0; mi < 4; ++mi)
#pragma unroll
            for (int ni = 0; ni < 4; ++ni) {
                int col = n0 + wc * 64 + ni * 16 + l15;
#pragma unroll
                for (int j = 0; j < 4; ++j) {
                    int row = m0 + wr * 64 + mi * 16 + (l4 << 2) + j;
                    out[(size_t)row * HID + col] = f2bf((acc[mi][ni][j] + bi[ni]) * scale);
                }
            }
    } else {
        float* out = (float*)O0;
#pragma unroll
        for (int mi = 0; mi < 4; ++mi)
#pragma unroll
            for (int ni = 0; ni < 4; ++ni) {
                int col = n0 + wc * 64 + ni * 16 + l15;
#pragma unroll
                for (int j = 0; j < 4; ++j) {
                    int row = m0 + wr * 64 + mi * 16 + (l4 << 2) + j;
                    out[(size_t)row * HID + col] = acc[mi][ni][j] + bi[ni];
                }
            }
    }
}

// ---------------- flash attention v7 = v5 structure, [B][S][HID] operands ----------------
// v5 (measured 61us, the best structure): 8 waves x 16 q-rows, K shared in LDS
// (double-buffered, gll16), role-split staging (waves 4-7 K, waves 0-3 V),
// XCD-affine grid (bh%8 = XCD). v7 only changes operand layout to the GEMM's
// natural [B][S][HID] (row stride HID, head offset h*64) -> GEMM epilogue is
// fully coalesced; staging patterns here are stride-agnostic.
__global__ void __launch_bounds__(512, 4)
attn_kernel(const u16* __restrict__ Q, const u16* __restrict__ Kp,
            const u16* __restrict__ V, u16* __restrict__ CTX) {
    __shared__ u16 Klds[2][64 * 64];   // [buf][key][d] swizzled: byte = key*128 + ((d*2)^((key&7)<<4))
    __shared__ u16 Vt[2][64 * 64];     // [buf][d][key] swizzled: byte = d*128 + ((key*2)^((d&7)<<4))
    __shared__ u16 Plds[8][16 * 64];   // per-wave [q][key] swizzled: byte = q*128 + ((key*2)^((q&7)<<4))
    const int tid = threadIdx.x, lane = tid & 63, wid = tid >> 6;
    const int l15 = lane & 15, l4 = lane >> 4;
    const int bh = blockIdx.x;                 // bh on x -> XCD affinity (id%8 = bh%8)
    const int b = bh >> 4, h = bh & 15;
    const size_t base = (size_t)b * SEQ * HID + h * HD;   // [B][S][HID] layout
    const int q0 = blockIdx.y * 128 + wid * 16;
    const bool kstager = (tid >= 256);         // waves 4-7 stage K, waves 0-3 stage V

    // Q fragment (B-operand): lane holds Q[q0+l15][kf*32 + l4*8 .. +7]
    bf16x8 qf[2];
#pragma unroll
    for (int kf = 0; kf < 2; ++kf)
        qf[kf] = *(const bf16x8*)(Q + base + (size_t)(q0 + l15) * HID + kf * 32 + l4 * 8);

    f32x4 acc[4] = {};                 // col=l15 -> d=nd*16+l15, row=l4*4+j -> q
    float m = -__builtin_inff();
    float lsum = 0.f;                  // per-lane partial

    const int tv = tid & 255;          // V-stager index (waves 0-3)
    const int k2 = tv & 31;            // keys 2k2, 2k2+1
    const int d0 = (tv >> 5) * 8;      // d-group
    const int tk = tid - 256;          // K-stager index (waves 4-7)
    u16* Pw = Plds[wid];

    auto stageK = [&](int buf, int kt) {   // waves 4-7 only: 2 gll16 each (512 slots)
#pragma unroll
        for (int i = 0; i < 2; ++i) {
            int slot = tk + i * 256;
            int krow = slot >> 3;
            int kg   = (slot & 7) ^ (krow & 7);
            gll16(Kp + base + (size_t)(kt * 64 + krow) * HID + kg * 8,
                  (char*)&Klds[buf][0] + slot * 16);
        }
    };

    auto writeV = [&](int buf, uint4 va, uint4 vb) {   // waves 0-3 only
        u16x8 pa = __builtin_bit_cast(u16x8, va);
        u16x8 pb = __builtin_bit_cast(u16x8, vb);
#pragma unroll
        for (int j = 0; j < 8; ++j) {
            uint32_t w = (uint32_t)pa[j] | ((uint32_t)pb[j] << 16);
            *(uint32_t*)((char*)&Vt[buf][0] + (d0 + j) * 128 + ((4 * k2) ^ (j << 4))) = w;
        }
    };

    // prologue: K0 -> LDS (waves 4-7), V0 -> regs -> Vt[0] (waves 0-3)
    if (kstager) {
        stageK(0, 0);
        asm volatile("s_waitcnt vmcnt(0)" ::: "memory");
    } else {
        uint4 va = *(const uint4*)(V + base + (size_t)(2 * k2) * HID + d0);
        uint4 vb = *(const uint4*)(V + base + (size_t)(2 * k2 + 1) * HID + d0);
        writeV(0, va, vb);
    }
    __syncthreads();

    for (int t = 0; t < SEQ / 64; ++t) {
        const int buf = t & 1;
        const bool hn = (t + 1) < SEQ / 64;

        // ---- issue next tile's staging loads early ----
        uint4 va, vb;
        if (hn) {
            if (kstager) {
                stageK(buf ^ 1, t + 1);
            } else {
                va = *(const uint4*)(V + base + (size_t)((t + 1) * 64 + 2 * k2) * HID + d0);
                vb = *(const uint4*)(V + base + (size_t)((t + 1) * 64 + 2 * k2 + 1) * HID + d0);
            }
        }

        // ---- S^T = K @ Q^T : col=l15=q, row = key = ni*16 + l4*4 + j ----
        f32x4 st[4] = {};
        __builtin_amdgcn_s_setprio(1);
#pragma unroll
        for (int ni = 0; ni < 4; ++ni) {
            int kr = ni * 16 + l15;
            const char* kb = (const char*)&Klds[buf][0] + kr * 128;
            bf16x8 k0 = *(const bf16x8*)(kb + ((l4 * 16) ^ ((kr & 7) << 4)));
            bf16x8 k1 = *(const bf16x8*)(kb + ((64 + l4 * 16) ^ ((kr & 7) << 4)));
            st[ni] = __builtin_amdgcn_mfma_f32_16x16x32_bf16(k0, qf[0], st[ni], 0, 0, 0);
            st[ni] = __builtin_amdgcn_mfma_f32_16x16x32_bf16(k1, qf[1], st[ni], 0, 0, 0);
        }
        __builtin_amdgcn_s_setprio(0);

        // ---- softmax, zero-shuffle common path (exp2 domain) ----
        float pmax = fmaxf(fmaxf(st[0][0], st[0][1]), fmaxf(st[0][2], st[0][3]));
#pragma unroll
        for (int ni = 1; ni < 4; ++ni)
            pmax = fmaxf(pmax, fmaxf(fmaxf(st[ni][0], st[ni][1]), fmaxf(st[ni][2], st[ni][3])));

        if (!__all(pmax <= m + 8.0f)) {        // rare: real max growth
            float t0 = fmaxf(pmax, __shfl_xor(pmax, 16));
            t0 = fmaxf(t0, __shfl_xor(t0, 32));
            float mnew  = fmaxf(m, t0);
            float alpha = EXP2(m - mnew);       // first tile: exp2(-inf)=0
            m = mnew;
            lsum *= alpha;
            float aj[4];
#pragma unroll
            for (int j = 0; j < 4; ++j) aj[j] = __shfl(alpha, l4 * 4 + j, 64);
#pragma unroll
            for (int nd = 0; nd < 4; ++nd)
#pragma unroll
                for (int j = 0; j < 4; ++j) acc[nd][j] *= aj[j];
        }

        float rs = 0.f;
#pragma unroll
        for (int ni = 0; ni < 4; ++ni)
#pragma unroll
            for (int j = 0; j < 4; ++j) {
                st[ni][j] = EXP2(st[ni][j] - m);   // bounded by 2^8
                rs += st[ni][j];
            }
        lsum += rs;                                // per-lane partial; reduce at end

        // ---- V stagers write Vt(t+1) (compiler waits on va/vb regs) ----
        if (hn && !kstager) writeV(buf ^ 1, va, vb);

        // ---- P -> per-wave LDS (packed bf16 pairs) ----
#pragma unroll
        for (int ni = 0; ni < 4; ++ni)
#pragma unroll
            for (int jp = 0; jp < 2; ++jp) {
                uint32_t w;
                asm("v_cvt_pk_bf16_f32 %0, %1, %2" : "=v"(w)
                    : "v"(st[ni][2 * jp]), "v"(st[ni][2 * jp + 1]));
                int key = ni * 16 + l4 * 4 + 2 * jp;
                *(uint32_t*)((char*)Pw + l15 * 128 + ((key * 2) ^ ((l15 & 7) << 4))) = w;
            }

        bf16x8 pf[2];
#pragma unroll
        for (int kc = 0; kc < 2; ++kc)
            pf[kc] = *(const bf16x8*)((char*)Pw + l15 * 128 + ((kc * 64 + l4 * 16) ^ ((l15 & 7) << 4)));

        // ---- ctx += P @ V ----
        __builtin_amdgcn_s_setprio(1);
#pragma unroll
        for (int kc = 0; kc < 2; ++kc)
#pragma unroll
            for (int nd = 0; nd < 4; ++nd) {
                int dr = nd * 16 + l15;
                bf16x8 vf = *(const bf16x8*)((char*)&Vt[buf][0] + dr * 128 +
                                             ((kc * 64 + l4 * 16) ^ ((dr & 7) << 4)));
                acc[nd] = __builtin_amdgcn_mfma_f32_16x16x32_bf16(pf[kc], vf, acc[nd], 0, 0, 0);
            }
        __builtin_amdgcn_s_setprio(0);

        // ---- K stagers drain their DMA just before the barrier (max overlap) ----
        if (hn && kstager) asm volatile("s_waitcnt vmcnt(0)" ::: "memory");
        asm volatile("s_waitcnt lgkmcnt(0)" ::: "memory");
        __builtin_amdgcn_s_barrier();
        asm volatile("" ::: "memory");
    }

    // epilogue: reduce per-lane lsum, then ctx/l -> bf16 [B][S][HID]
    lsum += __shfl_xor(lsum, 16);
    lsum += __shfl_xor(lsum, 32);      // q-uniform total for q=l15
    float lj[4];
#pragma unroll
    for (int j = 0; j < 4; ++j) lj[j] = 1.0f / __shfl(lsum, l4 * 4 + j, 64);
#pragma unroll
    for (int nd = 0; nd < 4; ++nd)
#pragma unroll
        for (int j = 0; j < 4; ++j) {
            int s = q0 + l4 * 4 + j;
            int d = nd * 16 + l15;
            CTX[base + (size_t)s * HID + d] = f2bf(acc[nd][j] * lj[j]);
        }
}

// ---------------- launch ----------------
extern "C" void kernel_launch(void* const* d_in, const int* in_sizes, int n_in,
                              void* d_out, int out_size, void* d_ws, size_t ws_size,
                              hipStream_t stream) {
    const float* x  = (const float*)d_in[0];
    const float* Wq = (const float*)d_in[1];
    const float* bq = (const float*)d_in[2];
    const float* Wk = (const float*)d_in[3];
    const float* bk = (const float*)d_in[4];
    const float* Wv = (const float*)d_in[5];
    const float* bv = (const float*)d_in[6];
    const float* Wo = (const float*)d_in[7];
    const float* bo = (const float*)d_in[8];
    float* out = (float*)d_out;

    char* ws = (char*)d_ws;
    u16* xpe = (u16*)(ws);                      // 8 MB : 4096x1024 bf16
    u16* wqb = (u16*)(ws + ((size_t)8  << 20)); // 2 MB each
    u16* wkb = (u16*)(ws + ((size_t)10 << 20));
    u16* wvb = (u16*)(ws + ((size_t)12 << 20));
    u16* wob = (u16*)(ws + ((size_t)14 << 20));
    u16* qb  = (u16*)(ws + ((size_t)16 << 20)); // 8 MB each, [B][S][HID]
    u16* kb  = (u16*)(ws + ((size_t)24 << 20));
    u16* vb  = (u16*)(ws + ((size_t)32 << 20));
    u16* ctx = (u16*)(ws + ((size_t)40 << 20)); // 8 MB, [B][S][HID]

    prep_x_kernel<<<dim3(4096), dim3(256), 0, stream>>>(x, xpe);
    convw4_kernel<<<dim3(1024, 4), dim3(256), 0, stream>>>(Wq, Wk, Wv, Wo, wqb, wkb, wvb, wob);

    gemm128_kernel<0><<<dim3(8, 32, 3), dim3(256), 0, stream>>>(
        xpe, wqb, wkb, wvb, bq, bk, bv, qb, kb, vb);

    attn_kernel<<<dim3(32, 16), dim3(512), 0, stream>>>(qb, kb, vb, ctx);

    gemm128_kernel<1><<<dim3(8, 32, 1), dim3(256), 0, stream>>>(
        ctx, wob, wob, wob, bo, bo, bo, out, out, out);
}